// Round 5
// baseline (474.500 us; speedup 1.0000x reference)
//
#include <hip/hip_runtime.h>
#include <cstdint>
#include <math.h>

// ---------------------------------------------------------------------------
// ParallelAttention (GPT-NeoX style), MI355X gfx950.
//   SEQ=2048 BATCH=2 HID=2048 NH=16 HD=128, causal mask, RoPE full head dim.
// INTERFACE (established R0-R7): fp32 inputs, fp32 output, inputs resolved by
//   element count (w_dense = LAST 4194304 match; mask unused).
// R9: GEMMs on m97 structure (bf16 pre-convert + global_load_lds w16).
// R10 FAILED: 512-thr attn + reg ping-pong prefetch -> VGPR spills.
// R11: attn 4-wave + gload_lds K/V (pre-swizzled src + XOR read). 133us.
// R12 FAILED: wvw placed at ws+32M ALIASED Vt (qkv_v wrote Vt over wvw while
//   other blocks still read it) -> absmax 0.28. The attn schedule was fine.
// R13: fix = wvw lives in d_out (33.5 MB scratch, dead until dense_gemm
//   overwrites it). All R12 attn features kept:
//   - DOUBLE-BUFFERED K/V: gload_lds prefetch of tile t+1 before computing
//     tile t; end-of-iter barrier drains vmcnt after compute. 80 KiB LDS,
//     2 blocks/CU, 1 barrier/tile.
//   - T13 defer-max (skip O-rescale when __all(rmax<=mst+8), log2 domain).
//   - mask-skip: only the diagonal tile pays causal cmp/cndmask.
//   - qkv_v pure gload_lds (V-weights pre-converted into wvw by cvt_inputs).
// MFMA 16x16x32 bf16: A/B row=lane&15, k=(lane>>4)*8+j; C/D col=lane&15,
//   row=(lane>>4)*4+reg (verified m89/m91).
// global_load_lds: LDS dest is wave-uniform base + lane*16B (m104/m108) --
//   LDS must be LINEAR, source address is per-lane (pre-swizzle there).
// ---------------------------------------------------------------------------

typedef unsigned short u16;
typedef __bf16 bf16x8 __attribute__((ext_vector_type(8)));
typedef float floatx4 __attribute__((ext_vector_type(4)));

#define SEQ 2048
#define BATCH 2
#define HID 2048
#define NH 16
#define HD 128

__device__ __forceinline__ u16 f2bf(float f) {
  union { float f; uint32_t u; } v; v.f = f;
  uint32_t u = v.u;
  return (u16)((u + 0x7FFFu + ((u >> 16) & 1u)) >> 16);
}

// pack 8 fp32 -> 8 bf16 (RNE) and store 16B
__device__ __forceinline__ void st8_bf16(u16* dst, const float* s) {
  uint32_t pk[4];
#pragma unroll
  for (int j = 0; j < 4; j++)
    pk[j] = (uint32_t)f2bf(s[2 * j]) | ((uint32_t)f2bf(s[2 * j + 1]) << 16);
  *(uint4*)dst = make_uint4(pk[0], pk[1], pk[2], pk[3]);
}

// async global->LDS, 16B per lane; lds base must be wave-uniform
__device__ __forceinline__ void gl16(const u16* g, u16* l) {
  __builtin_amdgcn_global_load_lds(
      (const __attribute__((address_space(1))) void*)g,
      (__attribute__((address_space(3))) void*)l, 16, 0, 0);
}

// ------- input conversion: w_qkv K/Q tiles, hidden, V tiles -> bf16 ---------
// wb tile order: [K head 0..15][Q head 0..15]; src K h = 3h+1, Q h = 3h.
// V tiles (blk >= 8192) -> wvw (lives in d_out scratch), src h = 3h+2.
__global__ __launch_bounds__(256) void cvt_inputs(
    const float* __restrict__ W, const float* __restrict__ Hid,
    u16* __restrict__ wb, u16* __restrict__ Ah, u16* __restrict__ wvw) {
  const int blk = blockIdx.x;
  const int c0 = threadIdx.x * 8;
  const float* src;
  u16* dst;
  if (blk < 4096) {
    int dt = blk >> 7, r = blk & 127;
    int srow = (dt < 16) ? ((dt * 3 + 1) * 128 + r) : (((dt - 16) * 3) * 128 + r);
    src = W + (size_t)srow * HID;
    dst = wb + (size_t)blk * HID;
  } else if (blk < 8192) {
    int r = blk - 4096;
    src = Hid + (size_t)r * HID;
    dst = Ah + (size_t)r * HID;
  } else {
    int v = blk - 8192;  // 0..2047
    int h = v >> 7, r = v & 127;
    src = W + (size_t)((h * 3 + 2) * 128 + r) * HID;
    dst = wvw + (size_t)v * HID;
  }
  float t[8];
  *(floatx4*)&t[0] = *(const floatx4*)(src + c0);
  *(floatx4*)&t[4] = *(const floatx4*)(src + c0 + 4);
  st8_bf16(dst + c0, t);
}

// ---------------- w_dense fp32 -> bf16 --------------------------------------
__global__ __launch_bounds__(256) void cvt_wd(const float* __restrict__ W,
                                              u16* __restrict__ wd) {
  const int r = blockIdx.x;
  const int c0 = threadIdx.x * 8;
  float t[8];
  const float* src = W + (size_t)r * HID;
  *(floatx4*)&t[0] = *(const floatx4*)(src + c0);
  *(floatx4*)&t[4] = *(const floatx4*)(src + c0 + 4);
  st8_bf16(wd + (size_t)r * HID + c0, t);
}

// ---------------- QK projection: bf16 @ bf16, gload_lds both operands -------
__global__ __launch_bounds__(256, 2) void qkv_qk(
    const u16* __restrict__ Ah, const u16* __restrict__ wb,
    const float* __restrict__ bias, u16* __restrict__ Qw,
    u16* __restrict__ Kw) {
  __shared__ __align__(16) u16 As[128 * 64];
  __shared__ __align__(16) u16 Bs[128 * 64];
  const int tid = threadIdx.x;
  const int wv = tid >> 6, lane = tid & 63;
  const int quad = lane >> 4, l16 = lane & 15;
  const int wt = blockIdx.x;  // 0..15 = K head wt, 16..31 = Q head wt-16
  const int bm = blockIdx.y;
  const int rowA0 = bm * 128;
  const int wm = (wv >> 1) * 64;
  const int wn = (wv & 1) * 32;
  const int ntoff[4] = {wn, wn + 16, wn + 64, wn + 80};

  const int lrow = wv * 32 + (lane >> 3);
  const int lcol = (lane & 7) * 8;
  const u16* Ag = Ah + (size_t)(rowA0 + lrow) * HID + lcol;
  const u16* Bg = wb + ((size_t)wt * 128 + lrow) * HID + lcol;
  u16* Al = &As[(wv * 32) * 64];  // wave-uniform
  u16* Bl = &Bs[(wv * 32) * 64];

  floatx4 acc[4][4];
#pragma unroll
  for (int i = 0; i < 4; i++)
#pragma unroll
    for (int j = 0; j < 4; j++) acc[i][j] = (floatx4){0.f, 0.f, 0.f, 0.f};

  for (int kb = 0; kb < HID; kb += 64) {
#pragma unroll
    for (int j = 0; j < 4; j++) {
      gl16(Ag + (size_t)j * 8 * HID + kb, Al + j * 8 * 64);
      gl16(Bg + (size_t)j * 8 * HID + kb, Bl + j * 8 * 64);
    }
    __syncthreads();  // drains vmcnt(0): LDS tiles ready
#pragma unroll
    for (int ks = 0; ks < 64; ks += 32) {
      bf16x8 af[4], bfr[4];
#pragma unroll
      for (int mi = 0; mi < 4; mi++)
        af[mi] = *(const bf16x8*)&As[(wm + mi * 16 + l16) * 64 + ks + quad * 8];
#pragma unroll
      for (int ni = 0; ni < 4; ni++)
        bfr[ni] = *(const bf16x8*)&Bs[(ntoff[ni] + l16) * 64 + ks + quad * 8];
#pragma unroll
      for (int mi = 0; mi < 4; mi++)
#pragma unroll
        for (int ni = 0; ni < 4; ni++)
          acc[mi][ni] = __builtin_amdgcn_mfma_f32_16x16x32_bf16(
              af[mi], bfr[ni], acc[mi][ni], 0, 0, 0);
    }
    __syncthreads();  // all waves done reading before next gload_lds overwrite
  }

  // epilogue: bias + RoPE (inline cos/sin)
  const int seg = (wt < 16) ? 1 : 0;  // 1=K, 0=Q
  const int head = wt & 15;
  u16* dst = seg ? Kw : Qw;
  float bv[4];
#pragma unroll
  for (int ni = 0; ni < 4; ni++)
    bv[ni] = bias[(head * 3 + seg) * 128 + ntoff[ni] + l16];
  const float RC = 0.20762050593045951f;  // log2(10000)/64
  const float f0 = exp2f(-(float)(wn + l16) * RC);
  const float f1 = exp2f(-(float)(wn + 16 + l16) * RC);

#pragma unroll
  for (int mi = 0; mi < 4; mi++) {
#pragma unroll
    for (int reg = 0; reg < 4; reg++) {
      int r = rowA0 + wm + mi * 16 + quad * 4 + reg;
      int s = r >> 1, b = r & 1;
      size_t base = ((size_t)(b * NH + head) * SEQ + s) * HD;
      float sv, cv;
      sincosf((float)s * f0, &sv, &cv);
      {
        float lo = acc[mi][0][reg] + bv[0];
        float hi = acc[mi][2][reg] + bv[2];
        dst[base + wn + l16] = f2bf(lo * cv - hi * sv);
        dst[base + wn + l16 + 64] = f2bf(hi * cv + lo * sv);
      }
      sincosf((float)s * f1, &sv, &cv);
      {
        float lo = acc[mi][1][reg] + bv[1];
        float hi = acc[mi][3][reg] + bv[3];
        dst[base + wn + 16 + l16] = f2bf(lo * cv - hi * sv);
        dst[base + wn + 16 + l16 + 64] = f2bf(hi * cv + lo * sv);
      }
    }
  }
}

// ---------------- V projection: pure gload_lds (wvw in d_out scratch) -------
__global__ __launch_bounds__(256, 2) void qkv_v(
    const u16* __restrict__ Ah, const u16* __restrict__ wvw,
    const float* __restrict__ bias, u16* __restrict__ Vt) {
  __shared__ __align__(16) u16 As[128 * 64];
  __shared__ __align__(16) u16 Bs[128 * 64];
  const int tid = threadIdx.x;
  const int wv = tid >> 6, lane = tid & 63;
  const int quad = lane >> 4, l16 = lane & 15;
  const int head = blockIdx.x;  // 0..15
  const int bm = blockIdx.y;
  const int rowA0 = bm * 128;
  const int wm = (wv >> 1) * 64;
  const int wn = (wv & 1) * 32;
  const int ntoff[4] = {wn, wn + 16, wn + 64, wn + 80};

  const int lrow = wv * 32 + (lane >> 3);
  const int lcol = (lane & 7) * 8;
  const u16* Ag = Ah + (size_t)(rowA0 + lrow) * HID + lcol;
  const u16* Bg = wvw + ((size_t)head * 128 + lrow) * HID + lcol;
  u16* Al = &As[(wv * 32) * 64];
  u16* Bl = &Bs[(wv * 32) * 64];

  floatx4 acc[4][4];
#pragma unroll
  for (int i = 0; i < 4; i++)
#pragma unroll
    for (int j = 0; j < 4; j++) acc[i][j] = (floatx4){0.f, 0.f, 0.f, 0.f};

  for (int kb = 0; kb < HID; kb += 64) {
#pragma unroll
    for (int j = 0; j < 4; j++) {
      gl16(Ag + (size_t)j * 8 * HID + kb, Al + j * 8 * 64);
      gl16(Bg + (size_t)j * 8 * HID + kb, Bl + j * 8 * 64);
    }
    __syncthreads();
#pragma unroll
    for (int ks = 0; ks < 64; ks += 32) {
      bf16x8 af[4], bfr[4];
#pragma unroll
      for (int mi = 0; mi < 4; mi++)
        af[mi] = *(const bf16x8*)&As[(wm + mi * 16 + l16) * 64 + ks + quad * 8];
#pragma unroll
      for (int ni = 0; ni < 4; ni++)
        bfr[ni] = *(const bf16x8*)&Bs[(ntoff[ni] + l16) * 64 + ks + quad * 8];
#pragma unroll
      for (int mi = 0; mi < 4; mi++)
#pragma unroll
        for (int ni = 0; ni < 4; ni++)
          acc[mi][ni] = __builtin_amdgcn_mfma_f32_16x16x32_bf16(
              af[mi], bfr[ni], acc[mi][ni], 0, 0, 0);
    }
    __syncthreads();
  }

  float bv[4];
#pragma unroll
  for (int ni = 0; ni < 4; ni++)
    bv[ni] = bias[(head * 3 + 2) * 128 + ntoff[ni] + l16];
#pragma unroll
  for (int mi = 0; mi < 4; mi++) {
#pragma unroll
    for (int ni = 0; ni < 4; ni++) {
      int d = ntoff[ni] + l16;
#pragma unroll
      for (int reg = 0; reg < 4; reg++) {
        int r = rowA0 + wm + mi * 16 + quad * 4 + reg;
        int s = r >> 1, b = r & 1;
        Vt[((size_t)(b * NH + head) * HD + d) * SEQ + s] =
            f2bf(acc[mi][ni][reg] + bv[ni]);
      }
    }
  }
}

// ---------------- flash attention: double-buffered K/V prefetch -------------
__global__ __launch_bounds__(256, 2) void attn(
    const u16* __restrict__ Qw, const u16* __restrict__ Kw,
    const u16* __restrict__ Vt, u16* __restrict__ ctx) {
  __shared__ __align__(16) u16 Ks[2][64 * 128];   // 32768 B
  __shared__ __align__(16) u16 Vs[2][128 * 64];   // 32768 B
  __shared__ __align__(16) u16 Pl[4][32 * 64];    // 16384 B  (= 80 KiB total)

  const int tid = threadIdx.x;
  const int wv = tid >> 6, lane = tid & 63;
  const int quad = lane >> 4, l16 = lane & 15;
  const int bh = blockIdx.y;
  const int b = bh >> 4, h = bh & 15;
  // balanced qt: co-resident pair (bid, bid+256) gets qt = x and 15-x.
  const int qt = (bh < 16) ? blockIdx.x : 15 - blockIdx.x;
  const int sw = qt * 128 + wv * 32;  // this wave's 32 q-rows
  const size_t bhoff = (size_t)bh * SEQ * HD;

  bf16x8 qf[2][4];
#pragma unroll
  for (int mi = 0; mi < 2; mi++)
#pragma unroll
    for (int kc = 0; kc < 4; kc++)
      qf[mi][kc] = *(const bf16x8*)&Qw[bhoff +
                                       (size_t)(sw + mi * 16 + l16) * HD +
                                       kc * 32 + quad * 8];

  floatx4 o[2][8];
#pragma unroll
  for (int mi = 0; mi < 2; mi++)
#pragma unroll
    for (int ni = 0; ni < 8; ni++) o[mi][ni] = (floatx4){0.f, 0.f, 0.f, 0.f};
  float mst[2][4], lst[2][4];
#pragma unroll
  for (int mi = 0; mi < 2; mi++)
#pragma unroll
    for (int r = 0; r < 4; r++) { mst[mi][r] = -1e30f; lst[mi][r] = 0.f; }

  const int nt = qt * 2 + 2;
  const float SCL2 = 0.088388347648318447f * 1.442695040888963f;
  const float MSK2 = -10000.0f * 1.442695040888963f;
  const float THR = 8.0f;  // defer-max threshold (log2 domain): P <= 2^8

// stage K/V tile tt into buffer bb; src pre-swizzled 16B unit u -> u^(row&7),
// LDS linear (read side applies same XOR).
#define STAGE(bb, tt)                                                          \
  {                                                                            \
    _Pragma("unroll") for (int i = 0; i < 4; i++) {                            \
      int c = i * 256 + tid;                                                   \
      int rk = c >> 4, uk = c & 15;                                            \
      gl16(&Kw[bhoff + (size_t)((tt) * 64 + rk) * HD + (uk ^ (rk & 7)) * 8],   \
           &Ks[bb][(i * 256 + wv * 64) * 8]);                                  \
      int rv_ = c >> 3, uv = c & 7;                                            \
      gl16(&Vt[bhoff + (size_t)rv_ * SEQ + (tt) * 64 + (uv ^ (rv_ & 7)) * 8],  \
           &Vs[bb][(i * 256 + wv * 64) * 8]);                                  \
    }                                                                          \
  }

  STAGE(0, 0);
  __syncthreads();  // drain: buf0 ready

  for (int t = 0; t < nt; t++) {
    const int cur = t & 1;
    if (t + 1 < nt) STAGE(cur ^ 1, t + 1);  // async prefetch; drained at barrier

    const bool active = (t * 64 <= sw + 31);
    if (active) {
      const bool diag = (t * 64 + 63 > sw);  // only tile needing causal mask
      floatx4 sa[2][4];
#pragma unroll
      for (int mi = 0; mi < 2; mi++)
#pragma unroll
        for (int ni = 0; ni < 4; ni++) sa[mi][ni] = (floatx4){0.f, 0.f, 0.f, 0.f};
      __builtin_amdgcn_s_setprio(1);
#pragma unroll
      for (int kc = 0; kc < 4; kc++) {
        bf16x8 kf[4];
#pragma unroll
        for (int ni = 0; ni < 4; ni++)
          kf[ni] = *(const bf16x8*)&Ks[cur][(ni * 16 + l16) * 128 +
                                            (((kc * 4 + quad) ^ (l16 & 7)) * 8)];
#pragma unroll
        for (int mi = 0; mi < 2; mi++)
#pragma unroll
          for (int ni = 0; ni < 4; ni++)
            sa[mi][ni] = __builtin_amdgcn_mfma_f32_16x16x32_bf16(
                qf[mi][kc], kf[ni], sa[mi][ni], 0, 0, 0);
      }
      __builtin_amdgcn_s_setprio(0);

      // online softmax (log2 domain) with defer-max
      float alpha[2][4];
      int anyr = 0;
#pragma unroll
      for (int mi = 0; mi < 2; mi++) {
#pragma unroll
        for (int reg = 0; reg < 4; reg++) {
          const int rr = mi * 16 + quad * 4 + reg;
          const int sq = sw + rr;
          float rv[4];
          if (diag) {
#pragma unroll
            for (int ni = 0; ni < 4; ni++) {
              int sk = t * 64 + ni * 16 + l16;
              float v = sa[mi][ni][reg] * SCL2;
              if (sk > sq) v = MSK2;
              rv[ni] = v;
            }
          } else {
#pragma unroll
            for (int ni = 0; ni < 4; ni++) rv[ni] = sa[mi][ni][reg] * SCL2;
          }
          float rmax = fmaxf(fmaxf(rv[0], rv[1]), fmaxf(rv[2], rv[3]));
          rmax = fmaxf(rmax, __shfl_xor(rmax, 1));
          rmax = fmaxf(rmax, __shfl_xor(rmax, 2));
          rmax = fmaxf(rmax, __shfl_xor(rmax, 4));
          rmax = fmaxf(rmax, __shfl_xor(rmax, 8));
          float al;
          if (__all(rmax <= mst[mi][reg] + THR)) {
            al = 1.0f;  // defer: keep old max, skip rescale
          } else {
            float mn = fmaxf(mst[mi][reg], rmax);
            al = exp2f(mst[mi][reg] - mn);
            mst[mi][reg] = mn;
            anyr = 1;
          }
          const float m0 = mst[mi][reg];
          float rs = 0.f;
#pragma unroll
          for (int ni = 0; ni < 4; ni++) {
            float p = exp2f(rv[ni] - m0);
            rs += p;
            Pl[wv][rr * 64 + ((ni * 16 + l16) ^ ((rr & 7) << 3))] = f2bf(p);
          }
          rs += __shfl_xor(rs, 1);
          rs += __shfl_xor(rs, 2);
          rs += __shfl_xor(rs, 4);
          rs += __shfl_xor(rs, 8);
          lst[mi][reg] = lst[mi][reg] * al + rs;
          alpha[mi][reg] = al;
        }
      }
      if (anyr) {  // wave-uniform: rescale only when some row's max moved
#pragma unroll
        for (int mi = 0; mi < 2; mi++)
#pragma unroll
          for (int ni = 0; ni < 8; ni++)
#pragma unroll
            for (int reg = 0; reg < 4; reg++)
              o[mi][ni][reg] *= alpha[mi][reg];
      }

      // PV: P is wave-private (same-wave ds ordering) -> no barrier
      __builtin_amdgcn_s_setprio(1);
#pragma unroll
      for (int kc = 0; kc < 2; kc++) {
        bf16x8 pf[2];
#pragma unroll
        for (int mi = 0; mi < 2; mi++)
          pf[mi] = *(const bf16x8*)&Pl[wv][(mi * 16 + l16) * 64 +
                                           ((kc * 32 + quad * 8) ^
                                            ((l16 & 7) << 3))];
#pragma unroll
        for (int ni = 0; ni < 8; ni++) {
          bf16x8 vf = *(const bf16x8*)&Vs[cur][(ni * 16 + l16) * 64 +
                                               (((kc * 4 + quad) ^ (l16 & 7)) *
                                                8)];
#pragma unroll
          for (int mi = 0; mi < 2; mi++)
            o[mi][ni] = __builtin_amdgcn_mfma_f32_16x16x32_bf16(
                pf[mi], vf, o[mi][ni], 0, 0, 0);
        }
      }
      __builtin_amdgcn_s_setprio(0);
    }
    __syncthreads();  // joins waves + drains prefetch vmcnt: next buf ready
  }

  // final 1/l and store ctx [s][b][h*128+d]
#pragma unroll
  for (int mi = 0; mi < 2; mi++) {
#pragma unroll
    for (int reg = 0; reg < 4; reg++) {
      float inv = 1.0f / lst[mi][reg];
      int sq = sw + mi * 16 + quad * 4 + reg;
      size_t rbase = ((size_t)(sq * BATCH + b)) * HID + h * HD;
#pragma unroll
      for (int ni = 0; ni < 8; ni++)
        ctx[rbase + ni * 16 + l16] = f2bf(o[mi][ni][reg] * inv);
    }
  }
#undef STAGE
}

// ---------- dense GEMM (ctx bf16 @ wd bf16, gload_lds both) -> FP32 out -----
__global__ __launch_bounds__(256, 2) void dense_gemm(
    const u16* __restrict__ A, const u16* __restrict__ Wd,
    float* __restrict__ out) {
  __shared__ __align__(16) u16 As[128 * 64];
  __shared__ __align__(16) u16 Bs[128 * 64];
  const int tid = threadIdx.x;
  const int wv = tid >> 6, lane = tid & 63;
  const int quad = lane >> 4, l16 = lane & 15;
  const int bn = blockIdx.x, bm = blockIdx.y;
  const int rowA0 = bm * 128, rowB0 = bn * 128;
  const int wm = (wv >> 1) * 64;
  const int wn = (wv & 1) * 64;
  const int ntoff[4] = {wn, wn + 16, wn + 32, wn + 48};

  const int lrow = wv * 32 + (lane >> 3);
  const int lcol = (lane & 7) * 8;
  const u16* Ag = A + (size_t)(rowA0 + lrow) * HID + lcol;
  const u16* Bg = Wd + (size_t)(rowB0 + lrow) * HID + lcol;
  u16* Al = &As[(wv * 32) * 64];
  u16* Bl = &Bs[(wv * 32) * 64];

  floatx4 acc[4][4];
#pragma unroll
  for (int i = 0; i < 4; i++)
#pragma unroll
    for (int j = 0; j < 4; j++) acc[i][j] = (floatx4){0.f, 0.f, 0.f, 0.f};

  for (int kb = 0; kb < HID; kb += 64) {
#pragma unroll
    for (int j = 0; j < 4; j++) {
      gl16(Ag + (size_t)j * 8 * HID + kb, Al + j * 8 * 64);
      gl16(Bg + (size_t)j * 8 * HID + kb, Bl + j * 8 * 64);
    }
    __syncthreads();
#pragma unroll
    for (int ks = 0; ks < 64; ks += 32) {
      bf16x8 af[4], bfr[4];
#pragma unroll
      for (int mi = 0; mi < 4; mi++)
        af[mi] = *(const bf16x8*)&As[(wm + mi * 16 + l16) * 64 + ks + quad * 8];
#pragma unroll
      for (int ni = 0; ni < 4; ni++)
        bfr[ni] = *(const bf16x8*)&Bs[(ntoff[ni] + l16) * 64 + ks + quad * 8];
#pragma unroll
      for (int mi = 0; mi < 4; mi++)
#pragma unroll
        for (int ni = 0; ni < 4; ni++)
          acc[mi][ni] = __builtin_amdgcn_mfma_f32_16x16x32_bf16(
              af[mi], bfr[ni], acc[mi][ni], 0, 0, 0);
    }
    __syncthreads();
  }

#pragma unroll
  for (int mi = 0; mi < 4; mi++)
#pragma unroll
    for (int reg = 0; reg < 4; reg++) {
      int r = rowA0 + wm + mi * 16 + quad * 4 + reg;
#pragma unroll
      for (int ni = 0; ni < 4; ni++)
        out[(size_t)r * HID + bn * 128 + ntoff[ni] + l16] = acc[mi][ni][reg];
    }
}

// ---------------- bias passthrough (fp32 in -> fp32 out tail) ----------------
__global__ void copy_bias(const float* __restrict__ bd, float* __restrict__ out) {
  int i = blockIdx.x * 256 + threadIdx.x;
  if (i < HID) out[(size_t)SEQ * BATCH * HID + i] = bd[i];
}

extern "C" void kernel_launch(void* const* d_in, const int* in_sizes, int n_in,
                              void* d_out, int out_size, void* d_ws,
                              size_t ws_size, hipStream_t stream) {
  // Resolve inputs BY ELEMENT COUNT (dtype-independent):
  //   hidden 8388608, mask 4194304 (unused, precedes w_dense), w_qkv 12582912,
  //   b_qkv 6144, w_dense 4194304 (LAST match wins), b_dense 2048.
  const float *hidden = nullptr, *w_qkv = nullptr, *b_qkv = nullptr;
  const float *w_dense = nullptr, *b_dense = nullptr;
  for (int i = 0; i < n_in; i++) {
    long s = in_sizes[i];
    if (s == 8388608L) hidden = (const float*)d_in[i];
    else if (s == 12582912L) w_qkv = (const float*)d_in[i];
    else if (s == 6144L) b_qkv = (const float*)d_in[i];
    else if (s == 4194304L) w_dense = (const float*)d_in[i];  // last wins
    else if (s == 2048L) b_dense = (const float*)d_in[i];
  }
  float* out = (float*)d_out;

  // Workspace: 64 MiB, time-multiplexed:
  //   [ 0,16M) Qw                       ... later wd (8M, after attn)
  //   [16,32M) Kw
  //   [32,48M) wb K/Q tiles (dead after qkv_qk) -> Vt (written by qkv_v)
  //   [48,64M) Ah bf16 hidden -> ctx (after attn)
  // wvw (bf16 V-weight tiles, 8M) lives in d_out scratch (33.5M, dead until
  // dense_gemm overwrites it) -- fixes R12's wvw/Vt alias race.
  char* ws = (char*)d_ws;
  u16* Qw = (u16*)(ws);                 // [ 0,16M)
  u16* Kw = (u16*)(ws + 16777216ll);    // [16,32M)
  u16* Vt = (u16*)(ws + 33554432ll);    // [32,48M) after qkv_v
  u16* wb = (u16*)(ws + 33554432ll);    // [32,48M) K/Q bf16 tiles
  u16* Ah = (u16*)(ws + 50331648ll);    // [48,64M) bf16 hidden (dead by attn)
  u16* ctx = (u16*)(ws + 50331648ll);   // [48,64M) after attn
  u16* wd = (u16*)(ws);                 // [0,8M) bf16 w_dense (after attn)
  u16* wvw = (u16*)d_out;               // d_out scratch (dead until dense_gemm)

  cvt_inputs<<<dim3(10240), dim3(256), 0, stream>>>(w_qkv, hidden, wb, Ah, wvw);
  qkv_qk<<<dim3(32, 32), dim3(256), 0, stream>>>(Ah, wb, b_qkv, Qw, Kw);
  qkv_v<<<dim3(16, 32), dim3(256), 0, stream>>>(Ah, wvw, b_qkv, Vt);
  attn<<<dim3(16, 32), dim3(256), 0, stream>>>(Qw, Kw, Vt, ctx);
  cvt_wd<<<dim3(2048), dim3(256), 0, stream>>>(w_dense, wd);
  dense_gemm<<<dim3(16, 32), dim3(256), 0, stream>>>(ctx, wd, out);
  copy_bias<<<dim3(8), dim3(256), 0, stream>>>(b_dense, out);
}